// Round 10
// baseline (309.996 us; speedup 1.0000x reference)
//
#include <hip/hip_runtime.h>
#include <math.h>

#define D 256

__device__ __forceinline__ float wave_reduce_sum(float v) {
#pragma unroll
    for (int off = 32; off > 0; off >>= 1) v += __shfl_xor(v, off);
    return v;
}
__device__ __forceinline__ float wave_reduce_max(float v) {
#pragma unroll
    for (int off = 32; off > 0; off >>= 1) v = fmaxf(v, __shfl_xor(v, off));
    return v;
}

__device__ __forceinline__ float4 load_row_f32(const float* __restrict__ E_w,
                                               int idx, int lane) {
    return ((const float4*)(E_w + (size_t)idx * D))[lane];
}
__device__ __forceinline__ float4 load_row_i8(const signed char* __restrict__ Eq,
                                              const float* __restrict__ scales,
                                              int idx, int lane) {
    const char4 c = ((const char4*)(Eq + (size_t)idx * D))[lane];  // 256B row
    const float f = scales[idx];    // wave-uniform -> scalar load
    return make_float4(f * (float)c.x, f * (float)c.y,
                       f * (float)c.z, f * (float)c.w);
}
template <bool I8>
__device__ __forceinline__ float4 load_row(const float* __restrict__ E_w,
                                           const signed char* __restrict__ Eq,
                                           const float* __restrict__ scales,
                                           int idx, int lane) {
    return I8 ? load_row_i8(Eq, scales, idx, lane) : load_row_f32(E_w, idx, lane);
}

// Batched int8 row gather+accumulate: NB independent rows in flight.
template <int NB>
__device__ __forceinline__ void gather_batch_i8(
    const signed char* __restrict__ Eq, const float* __restrict__ scales,
    const int* __restrict__ idxp, int l, int lane, float4& acc) {
    int id[NB];
#pragma unroll
    for (int k = 0; k < NB; ++k) id[k] = idxp[l + k];
    char4 c[NB];
#pragma unroll
    for (int k = 0; k < NB; ++k)
        c[k] = ((const char4*)(Eq + (size_t)id[k] * D))[lane];
    float f[NB];
#pragma unroll
    for (int k = 0; k < NB; ++k) f[k] = scales[id[k]];
#pragma unroll
    for (int k = 0; k < NB; ++k) {
        acc.x += f[k] * (float)c[k].x;
        acc.y += f[k] * (float)c[k].y;
        acc.z += f[k] * (float)c[k].z;
        acc.w += f[k] * (float)c[k].w;
    }
}

__device__ __forceinline__ float dot4(const float4 a, const float4 b) {
    return a.x * b.x + a.y * b.y + a.z * b.z + a.w * b.w;
}

// ---------------------------------------------------------------------------
// K0: E_w fp32 -> int8 + per-row scale. Wave-per-row, 4 rows in flight.
// ---------------------------------------------------------------------------
__global__ __launch_bounds__(256) void convert_i8_kernel(
    const float* __restrict__ E_w, signed char* __restrict__ Eq,
    float* __restrict__ scales, int n_vocab) {
    const int lane = threadIdx.x & 63;
    const int gw   = (blockIdx.x * 256 + threadIdx.x) >> 6;
    const int nw   = (gridDim.x * 256) >> 6;

    for (int r0 = gw * 4; r0 < n_vocab; r0 += nw * 4) {
        const int n = min(4, n_vocab - r0);
        float4 v[4];
#pragma unroll
        for (int k = 0; k < 4; ++k)
            if (k < n) v[k] = load_row_f32(E_w, r0 + k, lane);
#pragma unroll
        for (int k = 0; k < 4; ++k) {
            if (k >= n) break;
            float mx = fmaxf(fmaxf(fabsf(v[k].x), fabsf(v[k].y)),
                             fmaxf(fabsf(v[k].z), fabsf(v[k].w)));
            mx = wave_reduce_max(mx);
            const float inv = (mx > 0.f) ? 127.f / mx : 0.f;
            const int qx = __float2int_rn(v[k].x * inv);
            const int qy = __float2int_rn(v[k].y * inv);
            const int qz = __float2int_rn(v[k].z * inv);
            const int qw = __float2int_rn(v[k].w * inv);
            const unsigned int packed =
                ((unsigned int)(unsigned char)(signed char)qx) |
                ((unsigned int)(unsigned char)(signed char)qy << 8) |
                ((unsigned int)(unsigned char)(signed char)qz << 16) |
                ((unsigned int)(unsigned char)(signed char)qw << 24);
            ((unsigned int*)(Eq + (size_t)(r0 + k) * D))[lane] = packed;
            if (lane == 0) scales[r0 + k] = mx * (1.f / 127.f);
        }
    }
}

// ---------------------------------------------------------------------------
// K1: blocks [0, nmain)             -> main super-blocks, G=8 batch rows each
//     blocks [nmain, nmain + BM)    -> negs, block-per-bm (exact R6 winner)
// Main super-block: wave owns 2 b's; phase 2 is an in-block 8-column GEMM so
// M_w is read 64x total instead of 512x (line-count model: -0.9M lines).
// ---------------------------------------------------------------------------
template <bool I8>
__global__ __launch_bounds__(256) void abae_fused_kernel(
    const int* __restrict__ pos, const int* __restrict__ negs,
    const float* __restrict__ E_w, const signed char* __restrict__ Eq,
    const float* __restrict__ scales, const float* __restrict__ T_w,
    const float* __restrict__ M_w, const float* __restrict__ M_b,
    const float* __restrict__ lin_w, const float* __restrict__ lin_b,
    float* __restrict__ r_s, float* __restrict__ z_s, float* __restrict__ z_n,
    int B, int BM, int nmain, int L, int n_asp) {
    const int t    = threadIdx.x;
    const int lane = t & 63;
    const int wv   = t >> 6;            // 0..3

    __shared__ float4 syy[8][64];       // 8KB: y_s per b (main) / sred (negs)
    __shared__ float  smy[8][256];      // 8KB: My per b
    __shared__ float  slog[4][2][16];   // per-wave aspect logits

    if (blockIdx.x >= (unsigned)nmain) {
        // ========== negs path: block-per-bm, 25 tokens/wave, depth-5 ========
        const int bm = blockIdx.x - nmain;
        const int* __restrict__ idxp = negs + (size_t)bm * L;
        const int C  = (L + 3) / 4;
        const int s0 = wv * C;
        const int e0 = min(L, s0 + C);

        float4 acc = make_float4(0.f, 0.f, 0.f, 0.f);
        int l = s0;
        if (I8) {
            for (; l + 5 <= e0; l += 5)
                gather_batch_i8<5>(Eq, scales, idxp, l, lane, acc);
            for (; l < e0; ++l) {
                const float4 v = load_row_i8(Eq, scales, idxp[l], lane);
                acc.x += v.x; acc.y += v.y; acc.z += v.z; acc.w += v.w;
            }
        } else {
            for (; l < e0; ++l) {
                const float4 v = load_row_f32(E_w, idxp[l], lane);
                acc.x += v.x; acc.y += v.y; acc.z += v.z; acc.w += v.w;
            }
        }
        syy[wv][lane] = acc;
        __syncthreads();
        if (wv == 0) {
            float4 z  = syy[0][lane];
            const float4 a1 = syy[1][lane], a2 = syy[2][lane], a3 = syy[3][lane];
            const float invL = 1.f / (float)L;
            z.x = (z.x + a1.x + a2.x + a3.x) * invL;
            z.y = (z.y + a1.y + a2.y + a3.y) * invL;
            z.z = (z.z + a1.z + a2.z + a3.z) * invL;
            z.w = (z.w + a1.w + a2.w + a3.w) * invL;
            float ss = dot4(z, z);
            ss = wave_reduce_sum(ss);
            const float inv = 1.f / fmaxf(sqrtf(ss), 1e-12f);
            z.x *= inv; z.y *= inv; z.z *= inv; z.w *= inv;
            ((float4*)(z_n + (size_t)bm * D))[lane] = z;
        }
        return;
    }

    // ==================== main super-block: 8 b's, wave owns 2 ==============
    const int b0 = blockIdx.x * 8;
    const int bj0 = b0 + wv * 2;        // wave's first b
    const float invL = 1.f / (float)L;

    // ---- phase 1: y_s per owned b (depth-5 int8 batches) ----
#pragma unroll
    for (int j = 0; j < 2; ++j) {
        const int b = bj0 + j;
        float4 acc = make_float4(0.f, 0.f, 0.f, 0.f);
        if (b < B) {
            const int* __restrict__ posb = pos + (size_t)b * L;
            int l = 0;
            if (I8) {
                for (; l + 5 <= L; l += 5)
                    gather_batch_i8<5>(Eq, scales, posb, l, lane, acc);
            }
            for (; l < L; ++l) {
                const float4 v = load_row<I8>(E_w, Eq, scales, posb[l], lane);
                acc.x += v.x; acc.y += v.y; acc.z += v.z; acc.w += v.w;
            }
        }
        acc.x *= invL; acc.y *= invL; acc.z *= invL; acc.w *= invL;
        syy[wv * 2 + j][lane] = acc;
    }
    __syncthreads();

    // ---- phase 2: in-block GEMM  My[bb][r] = M_b[r] + M_w[r,:].y[bb] ----
    // wave handles 64 rows, 2 at a time; 8 b-columns share each row load.
    for (int r = wv * 64; r < wv * 64 + 64; r += 2) {
        const float4 m0 = ((const float4*)(M_w + (size_t)(r + 0) * D))[lane];
        const float4 m1 = ((const float4*)(M_w + (size_t)(r + 1) * D))[lane];
        float p[16];
#pragma unroll
        for (int bb = 0; bb < 8; ++bb) {
            const float4 y = syy[bb][lane];
            p[bb]     = dot4(m0, y);
            p[8 + bb] = dot4(m1, y);
        }
#pragma unroll
        for (int off = 32; off > 0; off >>= 1) {
#pragma unroll
            for (int k = 0; k < 16; ++k) p[k] += __shfl_xor(p[k], off);
        }
        if (lane == 0) {
            const float mb0 = M_b[r], mb1 = M_b[r + 1];
#pragma unroll
            for (int bb = 0; bb < 8; ++bb) {
                smy[bb][r]     = p[bb] + mb0;
                smy[bb][r + 1] = p[8 + bb] + mb1;
            }
        }
    }
    __syncthreads();

    // ---- phase 3: z = sum_l e_l * exp(tanh(e_l . My)), wave-autonomous ----
    float4 my[2], zq[2];
#pragma unroll
    for (int j = 0; j < 2; ++j) {
        my[j] = ((const float4*)smy[wv * 2 + j])[lane];
        zq[j] = make_float4(0.f, 0.f, 0.f, 0.f);
    }
    {
        const int bA = bj0, bB = bj0 + 1;
        const bool okA = bA < B, okB = bB < B;
        const int* __restrict__ pA = pos + (size_t)(okA ? bA : 0) * L;
        const int* __restrict__ pB = pos + (size_t)(okB ? bB : 0) * L;
        int l = 0;
        for (; l + 2 <= L; l += 2) {
            const float4 e00 = load_row<I8>(E_w, Eq, scales, pA[l], lane);
            const float4 e01 = load_row<I8>(E_w, Eq, scales, pA[l + 1], lane);
            const float4 e10 = load_row<I8>(E_w, Eq, scales, pB[l], lane);
            const float4 e11 = load_row<I8>(E_w, Eq, scales, pB[l + 1], lane);
            float p00 = dot4(e00, my[0]), p01 = dot4(e01, my[0]);
            float p10 = dot4(e10, my[1]), p11 = dot4(e11, my[1]);
#pragma unroll
            for (int off = 32; off > 0; off >>= 1) {
                p00 += __shfl_xor(p00, off);
                p01 += __shfl_xor(p01, off);
                p10 += __shfl_xor(p10, off);
                p11 += __shfl_xor(p11, off);
            }
            const float w00 = expf(tanhf(p00)), w01 = expf(tanhf(p01));
            const float w10 = expf(tanhf(p10)), w11 = expf(tanhf(p11));
            zq[0].x += e00.x * w00 + e01.x * w01;
            zq[0].y += e00.y * w00 + e01.y * w01;
            zq[0].z += e00.z * w00 + e01.z * w01;
            zq[0].w += e00.w * w00 + e01.w * w01;
            zq[1].x += e10.x * w10 + e11.x * w11;
            zq[1].y += e10.y * w10 + e11.y * w11;
            zq[1].z += e10.z * w10 + e11.z * w11;
            zq[1].w += e10.w * w10 + e11.w * w11;
        }
        for (; l < L; ++l) {
            const float4 e0 = load_row<I8>(E_w, Eq, scales, pA[l], lane);
            const float4 e1 = load_row<I8>(E_w, Eq, scales, pB[l], lane);
            float p0 = dot4(e0, my[0]), p1 = dot4(e1, my[1]);
#pragma unroll
            for (int off = 32; off > 0; off >>= 1) {
                p0 += __shfl_xor(p0, off);
                p1 += __shfl_xor(p1, off);
            }
            const float w0 = expf(tanhf(p0)), w1 = expf(tanhf(p1));
            zq[0].x += e0.x * w0; zq[0].y += e0.y * w0;
            zq[0].z += e0.z * w0; zq[0].w += e0.w * w0;
            zq[1].x += e1.x * w1; zq[1].y += e1.y * w1;
            zq[1].z += e1.z * w1; zq[1].w += e1.w * w1;
        }
    }
    // l2norm + store z_s; keep normalized z in registers
#pragma unroll
    for (int j = 0; j < 2; ++j) {
        float ss = wave_reduce_sum(dot4(zq[j], zq[j]));
        const float inv = 1.f / fmaxf(sqrtf(ss), 1e-12f);
        zq[j].x *= inv; zq[j].y *= inv; zq[j].z *= inv; zq[j].w *= inv;
        const int b = bj0 + j;
        if (b < B) ((float4*)(z_s + (size_t)b * D))[lane] = zq[j];
    }

    // ---- phase 4: aspect logits (wave-local; lin_w rows shared by both b) --
    for (int a = 0; a < n_asp; ++a) {
        const float4 w4 = ((const float4*)(lin_w + (size_t)a * D))[lane];
        float p0 = dot4(zq[0], w4);
        float p1 = dot4(zq[1], w4);
#pragma unroll
        for (int off = 32; off > 0; off >>= 1) {
            p0 += __shfl_xor(p0, off);
            p1 += __shfl_xor(p1, off);
        }
        if (lane == 0) {
            const float lb = lin_b[a];
            slog[wv][0][a] = p0 + lb;
            slog[wv][1][a] = p1 + lb;
        }
    }
    // softmax params computed redundantly per lane (wave-coherent LDS)
    float mx[2] = {-1e30f, -1e30f}, sum[2] = {0.f, 0.f};
#pragma unroll
    for (int j = 0; j < 2; ++j) {
        for (int a = 0; a < n_asp; ++a) mx[j] = fmaxf(mx[j], slog[wv][j][a]);
        for (int a = 0; a < n_asp; ++a) sum[j] += expf(slog[wv][j][a] - mx[j]);
        sum[j] = 1.f / sum[j];
    }

    // ---- phase 5: r_s = l2norm(p @ T_w); T_w rows shared by both b ----
    float4 r0 = make_float4(0.f, 0.f, 0.f, 0.f);
    float4 r1 = make_float4(0.f, 0.f, 0.f, 0.f);
    for (int a = 0; a < n_asp; ++a) {
        const float4 t4 = ((const float4*)(T_w + (size_t)a * D))[lane];
        const float pa0 = expf(slog[wv][0][a] - mx[0]) * sum[0];
        const float pa1 = expf(slog[wv][1][a] - mx[1]) * sum[1];
        r0.x += pa0 * t4.x; r0.y += pa0 * t4.y;
        r0.z += pa0 * t4.z; r0.w += pa0 * t4.w;
        r1.x += pa1 * t4.x; r1.y += pa1 * t4.y;
        r1.z += pa1 * t4.z; r1.w += pa1 * t4.w;
    }
    {
        float ss0 = wave_reduce_sum(dot4(r0, r0));
        float ss1 = wave_reduce_sum(dot4(r1, r1));
        const float i0 = 1.f / fmaxf(sqrtf(ss0), 1e-12f);
        const float i1 = 1.f / fmaxf(sqrtf(ss1), 1e-12f);
        r0.x *= i0; r0.y *= i0; r0.z *= i0; r0.w *= i0;
        r1.x *= i1; r1.y *= i1; r1.z *= i1; r1.w *= i1;
        if (bj0 < B)     ((float4*)(r_s + (size_t)bj0 * D))[lane] = r0;
        if (bj0 + 1 < B) ((float4*)(r_s + (size_t)(bj0 + 1) * D))[lane] = r1;
    }
}

extern "C" void kernel_launch(void* const* d_in, const int* in_sizes, int n_in,
                              void* d_out, int out_size, void* d_ws, size_t ws_size,
                              hipStream_t stream) {
    const int*   pos   = (const int*)d_in[0];
    const int*   negs  = (const int*)d_in[1];
    const float* E_w   = (const float*)d_in[2];
    const float* T_w   = (const float*)d_in[3];
    const float* M_w   = (const float*)d_in[4];
    const float* M_b   = (const float*)d_in[5];
    const float* lin_w = (const float*)d_in[6];
    const float* lin_b = (const float*)d_in[7];
    float* out = (float*)d_out;

    const int d       = in_sizes[5];                 // 256 (M_b)
    const int n_asp   = in_sizes[7];                 // 14  (lin_b)
    const int M       = in_sizes[1] / in_sizes[0];   // 10
    const int B       = out_size / (d * (2 + M));    // 512
    const int L       = in_sizes[0] / B;             // 100
    const int n_vocab = in_sizes[2] / d;             // 100000
    (void)n_in;

    float* r_s = out;                              // [B, d]
    float* z_s = out + (size_t)B * d;              // [B, d]
    float* z_n = out + (size_t)2 * B * d;          // [B, M, d]

    const int BM    = B * M;                       // 5120
    const int nmain = (B + 7) / 8;                 // 64 super-blocks

    const size_t need = (size_t)n_vocab * D + (size_t)n_vocab * sizeof(float);
    const bool use_i8 = ws_size >= need;

    signed char* Eq = (signed char*)d_ws;
    float* scales   = (float*)(Eq + (size_t)n_vocab * D);

    if (use_i8) {
        convert_i8_kernel<<<2048, 256, 0, stream>>>(E_w, Eq, scales, n_vocab);
        abae_fused_kernel<true><<<nmain + BM, 256, 0, stream>>>(
            pos, negs, E_w, Eq, scales, T_w, M_w, M_b, lin_w, lin_b,
            r_s, z_s, z_n, B, BM, nmain, L, n_asp);
    } else {
        abae_fused_kernel<false><<<nmain + BM, 256, 0, stream>>>(
            pos, negs, E_w, (const signed char*)nullptr, (const float*)nullptr,
            T_w, M_w, M_b, lin_w, lin_b, r_s, z_s, z_n, B, BM, nmain, L, n_asp);
    }
}